// Round 5
// baseline (248.502 us; speedup 1.0000x reference)
//
#include <hip/hip_runtime.h>

// ---- problem constants ----
constexpr int B_ = 16, S_ = 1024, H_ = 16, DH_ = 64, DM_ = 1024;

typedef short bf16x8 __attribute__((ext_vector_type(8)));
typedef unsigned short us8 __attribute__((ext_vector_type(8)));
typedef unsigned short us4 __attribute__((ext_vector_type(4)));
typedef float f32x4 __attribute__((ext_vector_type(4)));

// f32 -> bf16 round-nearest-even (finite inputs)
__device__ __forceinline__ unsigned short f2b(float f) {
    unsigned u = __builtin_bit_cast(unsigned, f);
    u += 0x7FFFu + ((u >> 16) & 1u);
    return (unsigned short)(u >> 16);
}

// XOR swizzle for 64-wide bf16 LDS tiles (units: ushorts).
// Breaks the 16-way bank conflict of 128-byte row stride on ds_read_b128.
__device__ __forceinline__ int swz(int r, int c) { return (r << 6) + (c ^ ((r & 7) << 3)); }

// =====================================================================
// Kernel 1: per-head QKV projection.
// Q,K stored [B,H,S,64] bf16; V stored TRANSPOSED [B,H,64,S] bf16 so the
// attention PV B-fragment is a contiguous 16B LDS read.
// grid: B*H*(S/128) = 2048 blocks, 256 threads (4 waves).
// =====================================================================
__global__ __launch_bounds__(256) void proj_kernel(
    const float* __restrict__ x,
    const float* __restrict__ wq, const float* __restrict__ wk, const float* __restrict__ wv,
    const float* __restrict__ bq, const float* __restrict__ bk, const float* __restrict__ bv,
    unsigned short* __restrict__ qo, unsigned short* __restrict__ ko,
    unsigned short* __restrict__ vto)
{
    __shared__ unsigned short xs[128 * 64];
    __shared__ unsigned short wls[3][64 * 64];

    const int tid = threadIdx.x;
    const int bid = blockIdx.x;
    const int chunk = bid & 7, bh = bid >> 3;
    const int b = bh >> 4, h = bh & 15;
    const int s0 = chunk * 128;
    const int lane = tid & 63, w = tid >> 6;
    const int lr = lane & 15, lg = lane >> 4;

    // stage X chunk [128][64] f32 -> bf16 LDS (swizzled)
    #pragma unroll
    for (int it = 0; it < 4; ++it) {
        int item = it * 256 + tid;
        int row = item >> 3, c = (item & 7) << 3;
        const float* src = x + (size_t)(b * S_ + s0 + row) * DM_ + h * DH_ + c;
        float4 f0 = *(const float4*)src;
        float4 f1 = *(const float4*)(src + 4);
        us8 v = { f2b(f0.x), f2b(f0.y), f2b(f0.z), f2b(f0.w),
                  f2b(f1.x), f2b(f1.y), f2b(f1.z), f2b(f1.w) };
        *(us8*)&xs[swz(row, c)] = v;
    }
    // stage Wq/Wk/Wv for this head: each [64][64] row-major (out,in)
    const float* wsrc[3] = { wq, wk, wv };
    #pragma unroll
    for (int mtx = 0; mtx < 3; ++mtx) {
        #pragma unroll
        for (int it = 0; it < 2; ++it) {
            int item = it * 256 + tid;
            int row = item >> 3, c = (item & 7) << 3;
            const float* src = wsrc[mtx] + (size_t)h * 4096 + row * 64 + c;
            float4 f0 = *(const float4*)src;
            float4 f1 = *(const float4*)(src + 4);
            us8 v = { f2b(f0.x), f2b(f0.y), f2b(f0.z), f2b(f0.w),
                      f2b(f1.x), f2b(f1.y), f2b(f1.z), f2b(f1.w) };
            *(us8*)&wls[mtx][swz(row, c)] = v;
        }
    }
    __syncthreads();

    // A fragments (X rows) reused across all three matrices
    bf16x8 af[2][2];
    #pragma unroll
    for (int mt = 0; mt < 2; ++mt)
        #pragma unroll
        for (int k2 = 0; k2 < 2; ++k2)
            af[mt][k2] = *(const bf16x8*)&xs[swz(w * 32 + mt * 16 + lr, k2 * 32 + lg * 8)];

    const float* bias[3] = { bq, bk, bv };
    #pragma unroll
    for (int mtx = 0; mtx < 3; ++mtx) {
        #pragma unroll
        for (int mt = 0; mt < 2; ++mt) {
            #pragma unroll
            for (int n4 = 0; n4 < 4; ++n4) {
                f32x4 acc = { 0.f, 0.f, 0.f, 0.f };
                #pragma unroll
                for (int k2 = 0; k2 < 2; ++k2) {
                    bf16x8 bf_ = *(const bf16x8*)&wls[mtx][swz(n4 * 16 + lr, k2 * 32 + lg * 8)];
                    acc = __builtin_amdgcn_mfma_f32_16x16x32_bf16(af[mt][k2], bf_, acc, 0, 0, 0);
                }
                const int e = n4 * 16 + lr;
                const float bb = bias[mtx][h * DH_ + e];
                const int srow0 = s0 + w * 32 + mt * 16 + lg * 4;
                if (mtx == 0) {
                    #pragma unroll
                    for (int r = 0; r < 4; ++r)
                        qo[(size_t)(bh * S_ + srow0 + r) * 64 + e] = f2b(acc[r] + bb);
                } else if (mtx == 1) {
                    #pragma unroll
                    for (int r = 0; r < 4; ++r)
                        ko[(size_t)(bh * S_ + srow0 + r) * 64 + e] = f2b(acc[r] + bb);
                } else {
                    us4 pk = { f2b(acc[0] + bb), f2b(acc[1] + bb),
                               f2b(acc[2] + bb), f2b(acc[3] + bb) };
                    *(us4*)&vto[(size_t)(bh * 64 + e) * S_ + srow0] = pk;
                }
            }
        }
    }
}

// =====================================================================
// Kernel 2: flash attention. One block per (b,h, 128 q-rows); 4 waves x 32 rows.
// KV tiles of 64. Online softmax in log2 domain (scale*log2e folded).
// grid: 2048 blocks, 256 threads.
// =====================================================================
__global__ __launch_bounds__(256) void attn_kernel(
    const unsigned short* __restrict__ qw, const unsigned short* __restrict__ kw,
    const unsigned short* __restrict__ vtw, float* __restrict__ out)
{
    __shared__ unsigned short ks[64 * 64];
    __shared__ unsigned short vs[64 * 64];       // V transposed tile: [e][n]
    __shared__ unsigned short ps[4][32 * 64];    // per-wave P tile

    const int tid = threadIdx.x, lane = tid & 63, w = tid >> 6;
    int bid = blockIdx.x;
    bid = (bid & 7) * 256 + (bid >> 3);          // XCD-aware swizzle (2048 % 8 == 0)
    const int qt = bid & 7, bh = bid >> 3;
    const int b = bh >> 4, h = bh & 15;
    const int q0 = qt * 128;
    const int lr = lane & 15, lg = lane >> 4;

    // Q fragments held in registers for the whole kernel
    bf16x8 qf[2][2];
    #pragma unroll
    for (int mt = 0; mt < 2; ++mt)
        #pragma unroll
        for (int k2 = 0; k2 < 2; ++k2)
            qf[mt][k2] = *(const bf16x8*)
                &qw[(size_t)(bh * S_ + q0 + w * 32 + mt * 16 + lr) * 64 + k2 * 32 + lg * 8];

    float mx[2][4], ls[2][4];
    f32x4 oa[2][4];
    #pragma unroll
    for (int mt = 0; mt < 2; ++mt)
        #pragma unroll
        for (int r = 0; r < 4; ++r) { mx[mt][r] = -1e30f; ls[mt][r] = 0.f; }
    #pragma unroll
    for (int mt = 0; mt < 2; ++mt)
        #pragma unroll
        for (int e4 = 0; e4 < 4; ++e4) oa[mt][e4] = f32x4{ 0.f, 0.f, 0.f, 0.f };

    const float SC = 0.18033688011112042f;  // (1/sqrt(64)) * log2(e)

    for (int n0 = 0; n0 < S_; n0 += 64) {
        // ---- stage K tile [64][64] and Vt tile [64 e][64 n] ----
        #pragma unroll
        for (int it = 0; it < 2; ++it) {
            int item = it * 256 + tid;
            int row = item >> 3, c = (item & 7) << 3;
            *(us8*)&ks[swz(row, c)] =
                *(const us8*)&kw[(size_t)(bh * S_ + n0 + row) * 64 + c];
            *(us8*)&vs[swz(row, c)] =
                *(const us8*)&vtw[(size_t)(bh * 64 + row) * S_ + n0 + c];
        }
        __syncthreads();

        // ---- S = Q K^T (log2-scaled) ----
        float p[2][4][4];
        #pragma unroll
        for (int n4 = 0; n4 < 4; ++n4) {
            bf16x8 bf0 = *(const bf16x8*)&ks[swz(n4 * 16 + lr, 0 * 32 + lg * 8)];
            bf16x8 bf1 = *(const bf16x8*)&ks[swz(n4 * 16 + lr, 1 * 32 + lg * 8)];
            #pragma unroll
            for (int mt = 0; mt < 2; ++mt) {
                f32x4 acc = { 0.f, 0.f, 0.f, 0.f };
                acc = __builtin_amdgcn_mfma_f32_16x16x32_bf16(qf[mt][0], bf0, acc, 0, 0, 0);
                acc = __builtin_amdgcn_mfma_f32_16x16x32_bf16(qf[mt][1], bf1, acc, 0, 0, 0);
                #pragma unroll
                for (int r = 0; r < 4; ++r) p[mt][n4][r] = acc[r] * SC;
            }
        }

        // ---- online softmax (wave-parallel; 16-lane groups own rows) ----
        #pragma unroll
        for (int mt = 0; mt < 2; ++mt) {
            #pragma unroll
            for (int r = 0; r < 4; ++r) {
                float cm = fmaxf(fmaxf(p[mt][0][r], p[mt][1][r]),
                                 fmaxf(p[mt][2][r], p[mt][3][r]));
                #pragma unroll
                for (int msk = 1; msk < 16; msk <<= 1) cm = fmaxf(cm, __shfl_xor(cm, msk));
                float nm = fmaxf(mx[mt][r], cm);
                float al = __builtin_amdgcn_exp2f(mx[mt][r] - nm);
                mx[mt][r] = nm;
                float rs = 0.f;
                #pragma unroll
                for (int n4 = 0; n4 < 4; ++n4) {
                    p[mt][n4][r] = __builtin_amdgcn_exp2f(p[mt][n4][r] - nm);
                    rs += p[mt][n4][r];
                }
                #pragma unroll
                for (int msk = 1; msk < 16; msk <<= 1) rs += __shfl_xor(rs, msk);
                ls[mt][r] = ls[mt][r] * al + rs;
                #pragma unroll
                for (int e4 = 0; e4 < 4; ++e4) oa[mt][e4][r] *= al;
            }
        }

        // ---- write P to per-wave LDS (re-layout for A-fragment) ----
        #pragma unroll
        for (int mt = 0; mt < 2; ++mt)
            #pragma unroll
            for (int n4 = 0; n4 < 4; ++n4)
                #pragma unroll
                for (int r = 0; r < 4; ++r)
                    ps[w][swz(mt * 16 + lg * 4 + r, n4 * 16 + lr)] = f2b(p[mt][n4][r]);

        // ---- O += P V ----
        #pragma unroll
        for (int mt = 0; mt < 2; ++mt) {
            bf16x8 af0 = *(const bf16x8*)&ps[w][swz(mt * 16 + lr, 0 * 32 + lg * 8)];
            bf16x8 af1 = *(const bf16x8*)&ps[w][swz(mt * 16 + lr, 1 * 32 + lg * 8)];
            #pragma unroll
            for (int e4 = 0; e4 < 4; ++e4) {
                bf16x8 bv0 = *(const bf16x8*)&vs[swz(e4 * 16 + lr, 0 * 32 + lg * 8)];
                bf16x8 bv1 = *(const bf16x8*)&vs[swz(e4 * 16 + lr, 1 * 32 + lg * 8)];
                oa[mt][e4] = __builtin_amdgcn_mfma_f32_16x16x32_bf16(af0, bv0, oa[mt][e4], 0, 0, 0);
                oa[mt][e4] = __builtin_amdgcn_mfma_f32_16x16x32_bf16(af1, bv1, oa[mt][e4], 0, 0, 0);
            }
        }
        __syncthreads();
    }

    // ---- epilogue: normalize, store f32 ----
    #pragma unroll
    for (int mt = 0; mt < 2; ++mt)
        #pragma unroll
        for (int e4 = 0; e4 < 4; ++e4)
            #pragma unroll
            for (int r = 0; r < 4; ++r) {
                int srow = q0 + w * 32 + mt * 16 + lg * 4 + r;
                out[(size_t)(b * S_ + srow) * DM_ + h * DH_ + e4 * 16 + lr] =
                    oa[mt][e4][r] / ls[mt][r];
            }
}

extern "C" void kernel_launch(void* const* d_in, const int* in_sizes, int n_in,
                              void* d_out, int out_size, void* d_ws, size_t ws_size,
                              hipStream_t stream) {
    const float* x  = (const float*)d_in[0];
    const float* wq = (const float*)d_in[1];
    const float* wk = (const float*)d_in[2];
    const float* wv = (const float*)d_in[3];
    const float* bq = (const float*)d_in[4];
    const float* bk = (const float*)d_in[5];
    const float* bv = (const float*)d_in[6];
    float* out = (float*)d_out;

    const size_t per = (size_t)B_ * H_ * S_ * DH_;  // 16.78M bf16 elements
    unsigned short* qws  = (unsigned short*)d_ws;
    unsigned short* kws  = qws + per;
    unsigned short* vtws = kws + per;

    proj_kernel<<<dim3(2048), dim3(256), 0, stream>>>(x, wq, wk, wv, bq, bk, bv,
                                                      qws, kws, vtws);
    attn_kernel<<<dim3(2048), dim3(256), 0, stream>>>(qws, kws, vtws, out);
}